// Round 5
// baseline (524.578 us; speedup 1.0000x reference)
//
#include <hip/hip_runtime.h>
#include <math.h>

// Problem constants: B=4, N=2048, D=1024, H=16, DH=64
constexpr int Bc  = 4;
constexpr int Nc  = 2048;
constexpr int Dc  = 1024;
constexpr int Hc  = 16;
constexpr int DHc = 64;
constexpr int Mrows = Bc * Nc;  // 8192

typedef unsigned short ushortT;
typedef __attribute__((ext_vector_type(8))) short bf16x8;
typedef __attribute__((ext_vector_type(4))) unsigned short u16x4;
typedef __attribute__((ext_vector_type(4))) float f32x4;

// 1/sqrt(DH) * log2(e): folded into Q so softmax is exp2(s) directly.
#define QSCALE 0.18033688011112043f

// async global->LDS, 16B per lane; LDS dest must be wave-uniform base + lane*16
#define GLD_LDS16(g, l)                                                        \
  __builtin_amdgcn_global_load_lds(                                            \
      (const __attribute__((address_space(1))) void*)(g),                      \
      (__attribute__((address_space(3))) void*)(l), 16, 0, 0)

__device__ inline ushortT f2bf(float f) {
  unsigned int u = __float_as_uint(f);
  u += 0x7fffu + ((u >> 16) & 1u);  // round-to-nearest-even
  return (ushortT)(u >> 16);
}

// fast 2^x on the transcendental pipe (v_exp_f32)
__device__ inline float fexp2(float x) { return __builtin_amdgcn_exp2f(x); }

// ---------------------------------------------------------------------------
// fp32 -> bf16 conversion of x and the 4 weight matrices (unchanged, verified)
// ---------------------------------------------------------------------------
__global__ __launch_bounds__(256) void cvt_kernel(
    const float* __restrict__ x, const float* __restrict__ wq,
    const float* __restrict__ wk, const float* __restrict__ wv,
    const float* __restrict__ wo, ushortT* __restrict__ dst) {
  const int g = blockIdx.x * 256 + threadIdx.x;  // float4 index
  const float* src;
  size_t soff, doff;
  if (g < 2097152) {
    src = x;
    soff = (size_t)g * 4;
    doff = soff;
  } else {
    const int t = g - 2097152;
    const int w = t >> 18;
    const int off = t & 262143;
    src = (w == 0) ? wq : (w == 1) ? wk : (w == 2) ? wv : wo;
    soff = (size_t)off * 4;
    doff = 8388608u + (size_t)w * 1048576u + (size_t)off * 4;
  }
  float4 v = *(const float4*)(src + soff);
  ushort4 o = make_ushort4(f2bf(v.x), f2bf(v.y), f2bf(v.z), f2bf(v.w));
  *(ushort4*)(dst + doff) = o;
}

// ---------------------------------------------------------------------------
// MFMA GEMM C = A @ W^T.  BK=64 via two m97-layout 32-k panels: 32 MFMA per
// barrier pair. LDS 32 KB. T1 XCD-aware bijective workgroup swizzle kept
// (nwg%8==0 for both launches). setprio removed (lockstep 4-wave block:
// m190 precedent says mildly negative).
// QKV=1: wsel=bx>>3 selects Wq/Wk/Wv; Q output (wsel==0) pre-scaled by QSCALE.
// ---------------------------------------------------------------------------
template <int QKV>
__global__ __launch_bounds__(256) void mfma_gemm(const ushortT* __restrict__ A,
                                                 const ushortT* __restrict__ W0,
                                                 void* __restrict__ C0) {
  __shared__ ushortT As[2][128 * 32];  // [panel][row][32]
  __shared__ ushortT Bs[2][128 * 32];

  const int tid = threadIdx.x;
  const int wave = tid >> 6, lane = tid & 63;
  const int quad = lane >> 4, lrow = lane & 15;

  // T1: XCD swizzle of the flat workgroup id (bijective since nwg%8==0).
  const int gx = gridDim.x;
  const int nwg = gx * gridDim.y;
  const int orig = blockIdx.y * gx + blockIdx.x;
  const int swz = (orig & 7) * (nwg >> 3) + (orig >> 3);
  const int bx = swz % gx, by = swz / gx;

  const int wsel = QKV ? (bx >> 3) : 0;
  const int e0 = QKV ? ((bx & 7) * 128) : (bx * 128);
  const int m0 = by * 128;
  const ushortT* Wp = W0 + (size_t)wsel * (Dc * Dc);
  const float oscale = (QKV && wsel == 0) ? QSCALE : 1.0f;

  const ushortT* ag = A  + (size_t)(m0 + wave * 32 + (lane >> 2)) * Dc + (lane & 3) * 8;
  const ushortT* bg = Wp + (size_t)(e0 + wave * 32 + (lane >> 2)) * Dc + (lane & 3) * 8;
  const int lbase = wave * 1024 + lane * 8;

  f32x4 acc[4][4];
#pragma unroll
  for (int i = 0; i < 4; ++i)
#pragma unroll
    for (int j = 0; j < 4; ++j) acc[i][j] = (f32x4){0.f, 0.f, 0.f, 0.f};

  const int wm = (wave >> 1) * 64, wn = (wave & 1) * 64;

  for (int k0 = 0; k0 < Dc; k0 += 64) {
    __syncthreads();
#pragma unroll
    for (int p = 0; p < 2; ++p) {
      GLD_LDS16(ag + p * 32, &As[p][lbase]);
      GLD_LDS16(ag + p * 32 + 16 * Dc, &As[p][lbase + 512]);
      GLD_LDS16(bg + p * 32, &Bs[p][lbase]);
      GLD_LDS16(bg + p * 32 + 16 * Dc, &Bs[p][lbase + 512]);
    }
    ag += 64;
    bg += 64;
    __syncthreads();

#pragma unroll
    for (int p = 0; p < 2; ++p) {
      bf16x8 af[4], bf[4];
#pragma unroll
      for (int mt = 0; mt < 4; ++mt)
        af[mt] = *(const bf16x8*)(&As[p][(wm + mt * 16 + lrow) * 32 + quad * 8]);
#pragma unroll
      for (int nt = 0; nt < 4; ++nt)
        bf[nt] = *(const bf16x8*)(&Bs[p][(wn + nt * 16 + lrow) * 32 + quad * 8]);
#pragma unroll
      for (int mt = 0; mt < 4; ++mt)
#pragma unroll
        for (int nt = 0; nt < 4; ++nt)
          acc[mt][nt] = __builtin_amdgcn_mfma_f32_16x16x32_bf16(
              af[mt], bf[nt], acc[mt][nt], 0, 0, 0);
    }
  }

#pragma unroll
  for (int mt = 0; mt < 4; ++mt) {
#pragma unroll
    for (int nt = 0; nt < 4; ++nt) {
#pragma unroll
      for (int r = 0; r < 4; ++r) {
        const int m = m0 + wm + mt * 16 + quad * 4 + r;
        const int e = e0 + wn + nt * 16 + lrow;
        const float v = acc[mt][nt][r] * oscale;
        if (QKV) {
          const int b = m >> 11, n = m & 2047;
          const int h = e >> 6, dh = e & 63;
          ushortT* C = (ushortT*)C0 + (size_t)wsel * ((size_t)Mrows * Dc);
          C[(((size_t)(b * Hc + h)) * Nc + n) * DHc + dh] = f2bf(v);
        } else {
          ((float*)C0)[(size_t)m * Dc + e] = v;
        }
      }
    }
  }
}

// ---------------------------------------------------------------------------
// MFMA flash attention, fixed-m softmax. BQ=256, 256 threads (4 waves x 64
// Q-rows) -- round-0 structure (single Vt, 2 barriers/iter, LDS 62464 B,
// 2 blocks/CU) with a 2-deep S-pipeline:
//   QK(t+1) is computed INSIDE iteration t, into the alternate S register
//   set (sA/sB, pair-unrolled so indices are static). The QK MFMAs (matrix
//   pipe) overlap softmax(t) (VALU/trans pipe) -- they share no data. K is
//   staged distance-2 (DMA(t+2) issued at top of iter t into the dead Ks
//   buffer; drained by the end-of-iter barrier, a full iteration before its
//   QK). Evidence basis: attn is issue-latency-bound (round-3: L3-hot
//   dispatches with 10x less HBM traffic ran the exact same 127 us; round-4:
//   conflict reduction didn't help), and occupancy can't rise (512-thread
//   register wall r1/r3; grid fully resident at 2 blocks/CU).
// Ks pre-swizzled-source staging kept (conflicts 6.36M->4.26M measured).
// No setprio (round-4 regression suspect; m190 precedent).
// ---------------------------------------------------------------------------
__global__ __launch_bounds__(256, 2) void attn_mfma(const ushortT* __restrict__ Q,
                                                    const ushortT* __restrict__ K,
                                                    const ushortT* __restrict__ V,
                                                    ushortT* __restrict__ O) {
  __shared__ ushortT smemA[256 * 72];   // 36864 B (Qs staging uses first 32768)
  __shared__ ushortT Ks[2][64 * 64];    // 2 x 8192 B: ping-pong K tiles (swizzled chunks)
  __shared__ ushortT Vt[64 * 72];       // 9216 B: [dh][colp], single buffer

  const int tid = threadIdx.x;
  const int wave = tid >> 6, lane = tid & 63;
  const int quad = lane >> 4, lrow = lane & 15;
  const int bh = blockIdx.y;
  const int q0 = blockIdx.x * 256;

  const ushortT* qg = Q + (size_t)bh * Nc * DHc;
  const ushortT* kg = K + (size_t)bh * Nc * DHc;
  const ushortT* vg = V + (size_t)bh * Nc * DHc;

  // K staging swizzle: linear chunk slot (lane&3) receives global chunk
  // (lane&3) ^ ((key>>1)&3); key = kb + (lane>>2), kb%16==0
  // -> XOR term = (lane>>3)&3 (lane-only).
  const int ksw = (lane & 3) ^ ((lane >> 3) & 3);  // DMA source chunk
  const int krd = (lrow >> 1) & 3;                 // read-side XOR (key=nt*16+lrow)

  // Vt staging map: thread handles keys {kq,kq+16,kq+32,kq+48} x 4 dh.
  const int kq = tid & 15;
  const int dhg = (tid >> 4) * 4;

  // ---- prologue: stage Q (256 rows), Ks[0]<-K(0), vreg<-V(0) ----
#pragma unroll
  for (int c = 0; c < 2; ++c)
#pragma unroll
    for (int rh = 0; rh < 4; ++rh) {
      const int row = wave * 64 + rh * 16;
      GLD_LDS16(qg + (size_t)(q0 + row + (lane >> 2)) * DHc + c * 32 + (lane & 3) * 8,
                smemA + (c * 256 + row) * 32 + lane * 8);
    }
#pragma unroll
  for (int i = 0; i < 2; ++i) {
    const int cid = wave * 2 + i;
    const int c = cid & 1, kb = (cid >> 1) * 16;
    GLD_LDS16(kg + (size_t)(kb + (lane >> 2)) * DHc + c * 32 + ksw * 8,
              &Ks[0][(c * 64 + kb) * 32 + lane * 8]);
  }
  u16x4 vreg[4];
#pragma unroll
  for (int g = 0; g < 4; ++g)
    vreg[g] = *(const u16x4*)(vg + (size_t)(kq + 16 * g) * DHc + dhg);

  __syncthreads();  // Q + K(0) staged (drains vmcnt, incl. vreg loads)

  // Q fragments -> registers (A-operand: m=lrow, k=quad*8+j)
  bf16x8 af_q[4][2];
#pragma unroll
  for (int mt = 0; mt < 4; ++mt)
#pragma unroll
    for (int ks = 0; ks < 2; ++ks)
      af_q[mt][ks] = *(const bf16x8*)(smemA +
          ((ks * 256 + wave * 64 + mt * 16 + lrow) * 32 + quad * 8));

  // Vt <- V(0) (transpose+permute from regs)
  {
    ushortT tmp[4][4];
#pragma unroll
    for (int g = 0; g < 4; ++g)
#pragma unroll
      for (int d = 0; d < 4; ++d) tmp[d][g] = vreg[g][d];
#pragma unroll
    for (int d = 0; d < 4; ++d)
      *(u16x4*)(&Vt[(dhg + d) * 72 + kq * 4]) = *(const u16x4*)tmp[d];
  }

  // prefetch tile 1: V(1) regs + K(1) DMA into Ks[1]
#pragma unroll
  for (int g = 0; g < 4; ++g)
    vreg[g] = *(const u16x4*)(vg + (size_t)(64 + kq + 16 * g) * DHc + dhg);
#pragma unroll
  for (int i = 0; i < 2; ++i) {
    const int cid = wave * 2 + i;
    const int c = cid & 1, kb = (cid >> 1) * 16;
    GLD_LDS16(kg + (size_t)(64 + kb + (lane >> 2)) * DHc + c * 32 + ksw * 8,
              &Ks[1][(c * 64 + kb) * 32 + lane * 8]);
  }

  __syncthreads();  // af_q read before P overwrites Qs; Vt(0) visible; K(1) drained

  f32x4 sA[4][4], sB[4][4];
  f32x4 o_acc[4][4];
#pragma unroll
  for (int mt = 0; mt < 4; ++mt)
#pragma unroll
    for (int nt = 0; nt < 4; ++nt) o_acc[mt][nt] = (f32x4){0.f, 0.f, 0.f, 0.f};
  float l_i[16];
#pragma unroll
  for (int i = 0; i < 16; ++i) l_i[i] = 0.f;

  // QK(0) -> sA (reads Ks[0])
  {
    bf16x8 bf_k[4][2];
#pragma unroll
    for (int nt = 0; nt < 4; ++nt)
#pragma unroll
      for (int ks = 0; ks < 2; ++ks)
        bf_k[nt][ks] = *(const bf16x8*)(
            &Ks[0][(ks * 64 + nt * 16 + lrow) * 32 + (quad ^ krd) * 8]);
#pragma unroll
    for (int mt = 0; mt < 4; ++mt)
#pragma unroll
      for (int nt = 0; nt < 4; ++nt) {
        sA[mt][nt] = (f32x4){0.f, 0.f, 0.f, 0.f};
#pragma unroll
        for (int ks = 0; ks < 2; ++ks)
          sA[mt][nt] = __builtin_amdgcn_mfma_f32_16x16x32_bf16(
              af_q[mt][ks], bf_k[nt][ks], sA[mt][nt], 0, 0, 0);
      }
  }
  __syncthreads();  // all waves done QK(0) before body-0's DMA(2) hits Ks[0]

// ---- pipelined iteration body ----
// T: tile index (consumes S(T) from SIN). CUR = T&1 (static).
//   1. vreg <- V(T+1)            [PREF1]
//   2. DMA K(T+2) -> Ks[CUR]     [PREF2]  (K(T) is dead; drained at end barrier)
//   3. softmax(SIN) -> P LDS + l_i        (VALU/trans pipe)
//   4. QK(T+1) from Ks[CUR^1] -> SOUT     (matrix pipe; overlaps 3)
//   5. lgkm drain; PV(T): o_acc += P @ Vt
//   6. barrier; Vt <- vreg (V(T+1)); barrier (drains DMA K(T+2))
#define BODY(T, CUR, SIN, SOUT, PREF1, PREF2)                                  \
  {                                                                            \
    const int k0b = (T) * 64;                                                  \
    if (PREF1) {                                                               \
      _Pragma("unroll") for (int g = 0; g < 4; ++g)                            \
          vreg[g] = *(const u16x4*)(vg +                                       \
              (size_t)(k0b + 64 + kq + 16 * g) * DHc + dhg);                   \
    }                                                                          \
    if (PREF2) {                                                               \
      _Pragma("unroll") for (int i = 0; i < 2; ++i) {                          \
        const int cid = wave * 2 + i;                                          \
        const int cc = cid & 1, kb = (cid >> 1) * 16;                          \
        GLD_LDS16(kg + (size_t)(k0b + 128 + kb + (lane >> 2)) * DHc +          \
                      cc * 32 + ksw * 8,                                       \
                  &Ks[CUR][(cc * 64 + kb) * 32 + lane * 8]);                   \
      }                                                                        \
    }                                                                          \
    _Pragma("unroll") for (int mt = 0; mt < 4; ++mt) {                         \
      _Pragma("unroll") for (int r = 0; r < 4; ++r) {                          \
        const float p0 = fexp2(SIN[mt][0][r]);                                 \
        const float p1 = fexp2(SIN[mt][1][r]);                                 \
        const float p2 = fexp2(SIN[mt][2][r]);                                 \
        const float p3 = fexp2(SIN[mt][3][r]);                                 \
        l_i[mt * 4 + r] += (p0 + p1) + (p2 + p3);                              \
        const unsigned pk01 = __builtin_amdgcn_perm(                           \
            __float_as_uint(p1), __float_as_uint(p0), 0x07060302u);            \
        const unsigned pk23 = __builtin_amdgcn_perm(                           \
            __float_as_uint(p3), __float_as_uint(p2), 0x07060302u);            \
        const int prow = wave * 64 + mt * 16 + quad * 4 + r;                   \
        *(uint2*)(smemA + prow * 72 + lrow * 4) = make_uint2(pk01, pk23);      \
      }                                                                        \
    }                                                                          \
    if (PREF1) {                                                               \
      bf16x8 bf_k[4][2];                                                       \
      _Pragma("unroll") for (int nt = 0; nt < 4; ++nt)                         \
        _Pragma("unroll") for (int ks = 0; ks < 2; ++ks)                       \
            bf_k[nt][ks] = *(const bf16x8*)(                                   \
                &Ks[(CUR) ^ 1][(ks * 64 + nt * 16 + lrow) * 32 +               \
                               (quad ^ krd) * 8]);                             \
      _Pragma("unroll") for (int mt = 0; mt < 4; ++mt)                         \
        _Pragma("unroll") for (int nt = 0; nt < 4; ++nt) {                     \
          SOUT[mt][nt] = (f32x4){0.f, 0.f, 0.f, 0.f};                          \
          _Pragma("unroll") for (int ks = 0; ks < 2; ++ks)                     \
              SOUT[mt][nt] = __builtin_amdgcn_mfma_f32_16x16x32_bf16(          \
                  af_q[mt][ks], bf_k[nt][ks], SOUT[mt][nt], 0, 0, 0);          \
        }                                                                      \
    }                                                                          \
    asm volatile("s_waitcnt lgkmcnt(0)" ::: "memory");                         \
    {                                                                          \
      bf16x8 af_p[4][2], bf_v[4][2];                                           \
      _Pragma("unroll") for (int mt = 0; mt < 4; ++mt)                         \
        _Pragma("unroll") for (int ks = 0; ks < 2; ++ks)                       \
            af_p[mt][ks] = *(const bf16x8*)(smemA +                            \
                (wave * 64 + mt * 16 + lrow) * 72 + ks * 32 + quad * 8);       \
      _Pragma("unroll") for (int nt = 0; nt < 4; ++nt)                         \
        _Pragma("unroll") for (int ks = 0; ks < 2; ++ks)                       \
            bf_v[nt][ks] = *(const bf16x8*)(                                   \
                &Vt[(nt * 16 + lrow) * 72 + ks * 32 + quad * 8]);              \
      _Pragma("unroll") for (int mt = 0; mt < 4; ++mt)                         \
        _Pragma("unroll") for (int nt = 0; nt < 4; ++nt)                       \
          _Pragma("unroll") for (int ks = 0; ks < 2; ++ks)                     \
              o_acc[mt][nt] = __builtin_amdgcn_mfma_f32_16x16x32_bf16(         \
                  af_p[mt][ks], bf_v[nt][ks], o_acc[mt][nt], 0, 0, 0);         \
    }                                                                          \
    __syncthreads(); /* all waves done reading Vt(T) + Ks[CUR^1] QK */         \
    if (PREF1) {                                                               \
      ushortT tmp[4][4];                                                       \
      _Pragma("unroll") for (int g = 0; g < 4; ++g)                            \
        _Pragma("unroll") for (int d = 0; d < 4; ++d) tmp[d][g] = vreg[g][d];  \
      _Pragma("unroll") for (int d = 0; d < 4; ++d)                            \
          *(u16x4*)(&Vt[(dhg + d) * 72 + kq * 4]) = *(const u16x4*)tmp[d];     \
    }                                                                          \
    __syncthreads(); /* Vt(T+1) visible; DMA K(T+2) drained (vmcnt0) */        \
  }

#pragma unroll 1
  for (int it = 0; it < 15; ++it) {
    BODY(2 * it,     0, sA, sB, true, true)
    BODY(2 * it + 1, 1, sB, sA, true, true)
  }
  BODY(30, 0, sA, sB, true, false)

  // ---- tail: tile 31 (softmax + PV only) ----
#pragma unroll
  for (int mt = 0; mt < 4; ++mt) {
#pragma unroll
    for (int r = 0; r < 4; ++r) {
      const float p0 = fexp2(sB[mt][0][r]);
      const float p1 = fexp2(sB[mt][1][r]);
      const float p2 = fexp2(sB[mt][2][r]);
      const float p3 = fexp2(sB[mt][3][r]);
      l_i[mt * 4 + r] += (p0 + p1) + (p2 + p3);
      const unsigned pk01 = __builtin_amdgcn_perm(
          __float_as_uint(p1), __float_as_uint(p0), 0x07060302u);
      const unsigned pk23 = __builtin_amdgcn_perm(
          __float_as_uint(p3), __float_as_uint(p2), 0x07060302u);
      const int prow = wave * 64 + mt * 16 + quad * 4 + r;
      *(uint2*)(smemA + prow * 72 + lrow * 4) = make_uint2(pk01, pk23);
    }
  }
  asm volatile("s_waitcnt lgkmcnt(0)" ::: "memory");
  {
    bf16x8 af_p[4][2], bf_v[4][2];
#pragma unroll
    for (int mt = 0; mt < 4; ++mt)
#pragma unroll
      for (int ks = 0; ks < 2; ++ks)
        af_p[mt][ks] = *(const bf16x8*)(smemA +
            (wave * 64 + mt * 16 + lrow) * 72 + ks * 32 + quad * 8);
#pragma unroll
    for (int nt = 0; nt < 4; ++nt)
#pragma unroll
      for (int ks = 0; ks < 2; ++ks)
        bf_v[nt][ks] = *(const bf16x8*)(
            &Vt[(nt * 16 + lrow) * 72 + ks * 32 + quad * 8]);
#pragma unroll
    for (int mt = 0; mt < 4; ++mt)
#pragma unroll
      for (int nt = 0; nt < 4; ++nt)
#pragma unroll
        for (int ks = 0; ks < 2; ++ks)
          o_acc[mt][nt] = __builtin_amdgcn_mfma_f32_16x16x32_bf16(
              af_p[mt][ks], bf_v[nt][ks], o_acc[mt][nt], 0, 0, 0);
  }

  // ---- final l reduction across the 16 lrow lanes ----
#pragma unroll
  for (int i = 0; i < 16; ++i) {
    float s = l_i[i];
#pragma unroll
    for (int off = 8; off >= 1; off >>= 1) s += __shfl_xor(s, off, 16);
    l_i[i] = s;
  }

  // ---- epilogue: O[b, n, h*64+dh] = o_acc / l ----
  const int b = bh / Hc, h = bh % Hc;
#pragma unroll
  for (int mt = 0; mt < 4; ++mt) {
#pragma unroll
    for (int r = 0; r < 4; ++r) {
      const float inv_l = 1.0f / l_i[mt * 4 + r];
      const int n = q0 + wave * 64 + mt * 16 + quad * 4 + r;
      const size_t base = ((size_t)b * Nc + n) * Dc + h * DHc;
#pragma unroll
      for (int nt = 0; nt < 4; ++nt)
        O[base + nt * 16 + lrow] = f2bf(o_acc[mt][nt][r] * inv_l);
    }
  }
}

// ---------------------------------------------------------------------------
extern "C" void kernel_launch(void* const* d_in, const int* in_sizes, int n_in,
                              void* d_out, int out_size, void* d_ws,
                              size_t ws_size, hipStream_t stream) {
  const float* x  = (const float*)d_in[0];
  const float* Wq = (const float*)d_in[2];
  const float* Wk = (const float*)d_in[3];
  const float* Wv = (const float*)d_in[4];
  const float* Wo = (const float*)d_in[5];

  ushortT* ws16 = (ushortT*)d_ws;
  ushortT* xb   = ws16;
  ushortT* wqb  = xb + (size_t)Mrows * Dc;
  ushortT* qkvb = wqb + 4 * (size_t)Dc * Dc;
  ushortT* qb   = qkvb;
  ushortT* kb   = qb + (size_t)Mrows * Dc;
  ushortT* vb   = kb + (size_t)Mrows * Dc;
  ushortT* aob  = vb + (size_t)Mrows * Dc;
  ushortT* wob  = wqb + 3 * (size_t)Dc * Dc;

  dim3 blk(256);
  hipLaunchKernelGGL(cvt_kernel, dim3(12288), blk, 0, stream, x, Wq, Wk, Wv, Wo,
                     ws16);

  hipLaunchKernelGGL((mfma_gemm<1>), dim3(24, Mrows / 128), blk, 0, stream, xb,
                     wqb, (void*)qkvb);

  hipLaunchKernelGGL(attn_mfma, dim3(Nc / 256, Bc * Hc), blk, 0, stream, qb,
                     kb, vb, aob);

  hipLaunchKernelGGL((mfma_gemm<0>), dim3(8, Mrows / 128), blk, 0, stream, aob,
                     wob, d_out);
}

// Round 6
// 498.874 us; speedup vs baseline: 1.0515x; 1.0515x over previous
//
#include <hip/hip_runtime.h>
#include <math.h>

// Problem constants: B=4, N=2048, D=1024, H=16, DH=64
constexpr int Bc  = 4;
constexpr int Nc  = 2048;
constexpr int Dc  = 1024;
constexpr int Hc  = 16;
constexpr int DHc = 64;
constexpr int Mrows = Bc * Nc;  // 8192

typedef unsigned short ushortT;
typedef __attribute__((ext_vector_type(8))) short bf16x8;
typedef __attribute__((ext_vector_type(4))) unsigned short u16x4;
typedef __attribute__((ext_vector_type(4))) float f32x4;

// 1/sqrt(DH) * log2(e): folded into Q so softmax is exp2(s) directly.
#define QSCALE 0.18033688011112043f

// async global->LDS, 16B per lane; LDS dest must be wave-uniform base + lane*16
#define GLD_LDS16(g, l)                                                        \
  __builtin_amdgcn_global_load_lds(                                            \
      (const __attribute__((address_space(1))) void*)(g),                      \
      (__attribute__((address_space(3))) void*)(l), 16, 0, 0)

__device__ inline ushortT f2bf(float f) {
  unsigned int u = __float_as_uint(f);
  u += 0x7fffu + ((u >> 16) & 1u);  // round-to-nearest-even
  return (ushortT)(u >> 16);
}

// fast 2^x on the transcendental pipe (v_exp_f32)
__device__ inline float fexp2(float x) { return __builtin_amdgcn_exp2f(x); }

// ---------------------------------------------------------------------------
// fp32 -> bf16 conversion of x and the 4 weight matrices (unchanged, verified)
// ---------------------------------------------------------------------------
__global__ __launch_bounds__(256) void cvt_kernel(
    const float* __restrict__ x, const float* __restrict__ wq,
    const float* __restrict__ wk, const float* __restrict__ wv,
    const float* __restrict__ wo, ushortT* __restrict__ dst) {
  const int g = blockIdx.x * 256 + threadIdx.x;  // float4 index
  const float* src;
  size_t soff, doff;
  if (g < 2097152) {
    src = x;
    soff = (size_t)g * 4;
    doff = soff;
  } else {
    const int t = g - 2097152;
    const int w = t >> 18;
    const int off = t & 262143;
    src = (w == 0) ? wq : (w == 1) ? wk : (w == 2) ? wv : wo;
    soff = (size_t)off * 4;
    doff = 8388608u + (size_t)w * 1048576u + (size_t)off * 4;
  }
  float4 v = *(const float4*)(src + soff);
  ushort4 o = make_ushort4(f2bf(v.x), f2bf(v.y), f2bf(v.z), f2bf(v.w));
  *(ushort4*)(dst + doff) = o;
}

// ---------------------------------------------------------------------------
// MFMA GEMM C = A @ W^T.  BK=64 via two m97-layout 32-k panels: 32 MFMA per
// barrier pair. LDS 32 KB. T1 XCD-aware bijective workgroup swizzle
// (nwg%8==0 for both launches). No setprio (lockstep block, m190).
// QKV=1: wsel=bx>>3 selects Wq/Wk/Wv; Q output (wsel==0) pre-scaled by QSCALE.
// ---------------------------------------------------------------------------
template <int QKV>
__global__ __launch_bounds__(256) void mfma_gemm(const ushortT* __restrict__ A,
                                                 const ushortT* __restrict__ W0,
                                                 void* __restrict__ C0) {
  __shared__ ushortT As[2][128 * 32];  // [panel][row][32]
  __shared__ ushortT Bs[2][128 * 32];

  const int tid = threadIdx.x;
  const int wave = tid >> 6, lane = tid & 63;
  const int quad = lane >> 4, lrow = lane & 15;

  // T1: XCD swizzle of the flat workgroup id (bijective since nwg%8==0).
  const int gx = gridDim.x;
  const int nwg = gx * gridDim.y;
  const int orig = blockIdx.y * gx + blockIdx.x;
  const int swz = (orig & 7) * (nwg >> 3) + (orig >> 3);
  const int bx = swz % gx, by = swz / gx;

  const int wsel = QKV ? (bx >> 3) : 0;
  const int e0 = QKV ? ((bx & 7) * 128) : (bx * 128);
  const int m0 = by * 128;
  const ushortT* Wp = W0 + (size_t)wsel * (Dc * Dc);
  const float oscale = (QKV && wsel == 0) ? QSCALE : 1.0f;

  const ushortT* ag = A  + (size_t)(m0 + wave * 32 + (lane >> 2)) * Dc + (lane & 3) * 8;
  const ushortT* bg = Wp + (size_t)(e0 + wave * 32 + (lane >> 2)) * Dc + (lane & 3) * 8;
  const int lbase = wave * 1024 + lane * 8;

  f32x4 acc[4][4];
#pragma unroll
  for (int i = 0; i < 4; ++i)
#pragma unroll
    for (int j = 0; j < 4; ++j) acc[i][j] = (f32x4){0.f, 0.f, 0.f, 0.f};

  const int wm = (wave >> 1) * 64, wn = (wave & 1) * 64;

  for (int k0 = 0; k0 < Dc; k0 += 64) {
    __syncthreads();
#pragma unroll
    for (int p = 0; p < 2; ++p) {
      GLD_LDS16(ag + p * 32, &As[p][lbase]);
      GLD_LDS16(ag + p * 32 + 16 * Dc, &As[p][lbase + 512]);
      GLD_LDS16(bg + p * 32, &Bs[p][lbase]);
      GLD_LDS16(bg + p * 32 + 16 * Dc, &Bs[p][lbase + 512]);
    }
    ag += 64;
    bg += 64;
    __syncthreads();

#pragma unroll
    for (int p = 0; p < 2; ++p) {
      bf16x8 af[4], bf[4];
#pragma unroll
      for (int mt = 0; mt < 4; ++mt)
        af[mt] = *(const bf16x8*)(&As[p][(wm + mt * 16 + lrow) * 32 + quad * 8]);
#pragma unroll
      for (int nt = 0; nt < 4; ++nt)
        bf[nt] = *(const bf16x8*)(&Bs[p][(wn + nt * 16 + lrow) * 32 + quad * 8]);
#pragma unroll
      for (int mt = 0; mt < 4; ++mt)
#pragma unroll
        for (int nt = 0; nt < 4; ++nt)
          acc[mt][nt] = __builtin_amdgcn_mfma_f32_16x16x32_bf16(
              af[mt], bf[nt], acc[mt][nt], 0, 0, 0);
    }
  }

#pragma unroll
  for (int mt = 0; mt < 4; ++mt) {
#pragma unroll
    for (int nt = 0; nt < 4; ++nt) {
#pragma unroll
      for (int r = 0; r < 4; ++r) {
        const int m = m0 + wm + mt * 16 + quad * 4 + r;
        const int e = e0 + wn + nt * 16 + lrow;
        const float v = acc[mt][nt][r] * oscale;
        if (QKV) {
          const int b = m >> 11, n = m & 2047;
          const int h = e >> 6, dh = e & 63;
          ushortT* C = (ushortT*)C0 + (size_t)wsel * ((size_t)Mrows * Dc);
          C[(((size_t)(b * Hc + h)) * Nc + n) * DHc + dh] = f2bf(v);
        } else {
          ((float*)C0)[(size_t)m * Dc + e] = v;
        }
      }
    }
  }
}

// ---------------------------------------------------------------------------
// MFMA flash attention, fixed-m softmax. BQ=256, 256 threads (4 waves x 64
// Q-rows). Round-6: DEFERRED-PV pipeline.
//   Iter t: QK(t) MFMA; PV(t-1) MFMA (independent, from held bf16 fragments
//   af_pH -- only 16 VGPRs, unlike r5's 128-reg f32 S-dbuf that spilled);
//   softmax(t) on VALU/trans overlaps PV(t-1) on the matrix pipe; P(t) ->
//   LDS -> af_pH reload; ONE barrier; Vt[(t+1)&1] <- V(t+1) from regs.
//   Vt slot discipline: PV(t-1) reads slot (t-1)&1 BEFORE the barrier; the
//   write to slot (t+1)&1 (same buffer) is AFTER it; the read of a slot is
//   always one barrier after its write. Ks ping-pong distance-1 (r0 scheme,
//   DMA drained by the barrier's implicit vmcnt(0)).
// Register budget (the r1/r3/r5 lesson: arch-VGPR ceiling ~128): held state
// af_q 16 + af_pH 16 + vreg 8 + transients ~60 -> fits; s_acc/o_acc in AGPRs.
// Ks pre-swizzled-source staging kept (conflicts 6.36M->4.26M measured).
// No setprio. LDS 71680 B -> 2 blocks/CU.
// ---------------------------------------------------------------------------
__device__ __forceinline__ f32x4 MFMA(bf16x8 a, bf16x8 b, f32x4 c) {
  return __builtin_amdgcn_mfma_f32_16x16x32_bf16(a, b, c, 0, 0, 0);
}

template <int KC, bool PVON, bool PREF>
__device__ __forceinline__ void attn_body(
    int T, const ushortT* __restrict__ kg, const ushortT* __restrict__ vg,
    ushortT* smemA, ushortT (&Ks)[2][64 * 64], ushortT (&Vt)[2][64 * 72],
    const bf16x8 (&af_q)[4][2], bf16x8 (&af_pH)[4][2], u16x4 (&vreg)[4],
    f32x4 (&o_acc)[4][4], float (&l_i)[16], int wave, int lane, int quad,
    int lrow, int ksw, int krd, int kq, int dhg) {
  const int k0b = T * 64;

  // ---- prefetch tile T+1: K DMA into the dead Ks slot; V into regs ----
  if (PREF) {
#pragma unroll
    for (int i = 0; i < 2; ++i) {
      const int cid = wave * 2 + i;
      const int c = cid & 1, kb = (cid >> 1) * 16;
      GLD_LDS16(kg + (size_t)(k0b + 64 + kb + (lane >> 2)) * DHc + c * 32 + ksw * 8,
                &Ks[KC ^ 1][(c * 64 + kb) * 32 + lane * 8]);
    }
#pragma unroll
    for (int g = 0; g < 4; ++g)
      vreg[g] = *(const u16x4*)(vg + (size_t)(k0b + 64 + kq + 16 * g) * DHc + dhg);
  }

  // ---- S = Q @ K(T)^T ----
  bf16x8 bf_k[4][2];
#pragma unroll
  for (int nt = 0; nt < 4; ++nt)
#pragma unroll
    for (int ks = 0; ks < 2; ++ks)
      bf_k[nt][ks] = *(const bf16x8*)(
          &Ks[KC][(ks * 64 + nt * 16 + lrow) * 32 + (quad ^ krd) * 8]);
  f32x4 s_acc[4][4];
#pragma unroll
  for (int mt = 0; mt < 4; ++mt)
#pragma unroll
    for (int nt = 0; nt < 4; ++nt) {
      s_acc[mt][nt] = (f32x4){0.f, 0.f, 0.f, 0.f};
#pragma unroll
      for (int ks = 0; ks < 2; ++ks)
        s_acc[mt][nt] = MFMA(af_q[mt][ks], bf_k[nt][ks], s_acc[mt][nt]);
    }

  // ---- O += P(T-1) @ V(T-1): independent of s_acc; matrix pipe runs this
  //      while softmax(T) below occupies VALU/trans ----
  if (PVON) {
    bf16x8 bf_v[4][2];
#pragma unroll
    for (int nt = 0; nt < 4; ++nt)
#pragma unroll
      for (int ks = 0; ks < 2; ++ks)
        bf_v[nt][ks] = *(const bf16x8*)(
            &Vt[KC ^ 1][(nt * 16 + lrow) * 72 + ks * 32 + quad * 8]);
#pragma unroll
    for (int mt = 0; mt < 4; ++mt)
#pragma unroll
      for (int nt = 0; nt < 4; ++nt)
#pragma unroll
        for (int ks = 0; ks < 2; ++ks)
          o_acc[mt][nt] = MFMA(af_pH[mt][ks], bf_v[nt][ks], o_acc[mt][nt]);
  }

  // ---- P(T) = exp2(S); partial row-sums; P -> LDS (bf16, colp layout) ----
#pragma unroll
  for (int mt = 0; mt < 4; ++mt) {
#pragma unroll
    for (int r = 0; r < 4; ++r) {
      const float p0 = fexp2(s_acc[mt][0][r]);
      const float p1 = fexp2(s_acc[mt][1][r]);
      const float p2 = fexp2(s_acc[mt][2][r]);
      const float p3 = fexp2(s_acc[mt][3][r]);
      l_i[mt * 4 + r] += (p0 + p1) + (p2 + p3);
      const unsigned pk01 = __builtin_amdgcn_perm(
          __float_as_uint(p1), __float_as_uint(p0), 0x07060302u);
      const unsigned pk23 = __builtin_amdgcn_perm(
          __float_as_uint(p3), __float_as_uint(p2), 0x07060302u);
      const int prow = wave * 64 + mt * 16 + quad * 4 + r;
      *(uint2*)(smemA + prow * 72 + lrow * 4) = make_uint2(pk01, pk23);
    }
  }
  // P is wave-local: drain LDS writes, then reload as A-fragments for the
  // NEXT iteration's PV. (Compiler ds ops, in-order per wave: safe.)
  asm volatile("s_waitcnt lgkmcnt(0)" ::: "memory");
#pragma unroll
  for (int mt = 0; mt < 4; ++mt)
#pragma unroll
    for (int ks = 0; ks < 2; ++ks)
      af_pH[mt][ks] = *(const bf16x8*)(smemA +
          (wave * 64 + mt * 16 + lrow) * 72 + ks * 32 + quad * 8);

  // single barrier: all waves' PV reads of Vt[KC^1] done; Ks[KC^1] DMA
  // drained (implicit vmcnt(0)); previous iter's Vt write now visible.
  __syncthreads();

  // ---- Vt[(T+1)&1] <- V(T+1) from regs (slot just vacated by PV above) ----
  if (PREF) {
    ushortT tmp[4][4];
#pragma unroll
    for (int g = 0; g < 4; ++g)
#pragma unroll
      for (int d = 0; d < 4; ++d) tmp[d][g] = vreg[g][d];
#pragma unroll
    for (int d = 0; d < 4; ++d)
      *(u16x4*)(&Vt[KC ^ 1][(dhg + d) * 72 + kq * 4]) = *(const u16x4*)tmp[d];
  }
}

__global__ __launch_bounds__(256, 2) void attn_mfma(const ushortT* __restrict__ Q,
                                                    const ushortT* __restrict__ K,
                                                    const ushortT* __restrict__ V,
                                                    ushortT* __restrict__ O) {
  __shared__ ushortT smemA[256 * 72];   // 36864 B (Qs staging uses first 32768)
  __shared__ ushortT Ks[2][64 * 64];    // 2 x 8192 B, swizzled chunks
  __shared__ ushortT Vt[2][64 * 72];    // 2 x 9216 B: [buf][dh][colp]

  const int tid = threadIdx.x;
  const int wave = tid >> 6, lane = tid & 63;
  const int quad = lane >> 4, lrow = lane & 15;
  const int bh = blockIdx.y;
  const int q0 = blockIdx.x * 256;

  const ushortT* qg = Q + (size_t)bh * Nc * DHc;
  const ushortT* kg = K + (size_t)bh * Nc * DHc;
  const ushortT* vg = V + (size_t)bh * Nc * DHc;

  // K staging swizzle (r4-verified): slot (lane&3) <- global chunk
  // (lane&3)^((lane>>3)&3); read-side XOR krd on quad.
  const int ksw = (lane & 3) ^ ((lane >> 3) & 3);
  const int krd = (lrow >> 1) & 3;

  // Vt staging map: thread handles keys {kq,kq+16,kq+32,kq+48} x 4 dh.
  const int kq = tid & 15;
  const int dhg = (tid >> 4) * 4;

  // ---- prologue: stage Q (256 rows), Ks[0]<-K(0), vreg<-V(0) ----
#pragma unroll
  for (int c = 0; c < 2; ++c)
#pragma unroll
    for (int rh = 0; rh < 4; ++rh) {
      const int row = wave * 64 + rh * 16;
      GLD_LDS16(qg + (size_t)(q0 + row + (lane >> 2)) * DHc + c * 32 + (lane & 3) * 8,
                smemA + (c * 256 + row) * 32 + lane * 8);
    }
#pragma unroll
  for (int i = 0; i < 2; ++i) {
    const int cid = wave * 2 + i;
    const int c = cid & 1, kb = (cid >> 1) * 16;
    GLD_LDS16(kg + (size_t)(kb + (lane >> 2)) * DHc + c * 32 + ksw * 8,
              &Ks[0][(c * 64 + kb) * 32 + lane * 8]);
  }
  u16x4 vreg[4];
#pragma unroll
  for (int g = 0; g < 4; ++g)
    vreg[g] = *(const u16x4*)(vg + (size_t)(kq + 16 * g) * DHc + dhg);

  __syncthreads();  // Q + K(0) staged; vreg V(0) loaded

  // Q fragments -> registers (A-operand: m=lrow, k=quad*8+j)
  bf16x8 af_q[4][2];
#pragma unroll
  for (int mt = 0; mt < 4; ++mt)
#pragma unroll
    for (int ks = 0; ks < 2; ++ks)
      af_q[mt][ks] = *(const bf16x8*)(smemA +
          ((ks * 256 + wave * 64 + mt * 16 + lrow) * 32 + quad * 8));

  // Vt[0] <- V(0)
  {
    ushortT tmp[4][4];
#pragma unroll
    for (int g = 0; g < 4; ++g)
#pragma unroll
      for (int d = 0; d < 4; ++d) tmp[d][g] = vreg[g][d];
#pragma unroll
    for (int d = 0; d < 4; ++d)
      *(u16x4*)(&Vt[0][(dhg + d) * 72 + kq * 4]) = *(const u16x4*)tmp[d];
  }
  __syncthreads();  // af_q read before P overwrites Qs; Vt[0] visible

  bf16x8 af_pH[4][2];
  f32x4 o_acc[4][4];
#pragma unroll
  for (int mt = 0; mt < 4; ++mt)
#pragma unroll
    for (int nt = 0; nt < 4; ++nt) o_acc[mt][nt] = (f32x4){0.f, 0.f, 0.f, 0.f};
  float l_i[16];
#pragma unroll
  for (int i = 0; i < 16; ++i) l_i[i] = 0.f;

  // t=0: no PV yet (af_pH empty); prefetch K(1)/V(1); Vt[1]<-V(1)
  attn_body<0, false, true>(0, kg, vg, smemA, Ks, Vt, af_q, af_pH, vreg,
                            o_acc, l_i, wave, lane, quad, lrow, ksw, krd, kq, dhg);
  // t = 1..30 (pair-unrolled, static slot parity)
#pragma unroll 1
  for (int it = 0; it < 15; ++it) {
    attn_body<1, true, true>(1 + 2 * it, kg, vg, smemA, Ks, Vt, af_q, af_pH,
                             vreg, o_acc, l_i, wave, lane, quad, lrow, ksw, krd, kq, dhg);
    attn_body<0, true, true>(2 + 2 * it, kg, vg, smemA, Ks, Vt, af_q, af_pH,
                             vreg, o_acc, l_i, wave, lane, quad, lrow, ksw, krd, kq, dhg);
  }
  // t=31: last QK + PV(30); no prefetch
  attn_body<1, true, false>(31, kg, vg, smemA, Ks, Vt, af_q, af_pH, vreg,
                            o_acc, l_i, wave, lane, quad, lrow, ksw, krd, kq, dhg);

  // ---- tail: PV(31) from af_pH + Vt[31&1 = 1] ----
  {
    bf16x8 bf_v[4][2];
#pragma unroll
    for (int nt = 0; nt < 4; ++nt)
#pragma unroll
      for (int ks = 0; ks < 2; ++ks)
        bf_v[nt][ks] = *(const bf16x8*)(
            &Vt[1][(nt * 16 + lrow) * 72 + ks * 32 + quad * 8]);
#pragma unroll
    for (int mt = 0; mt < 4; ++mt)
#pragma unroll
      for (int nt = 0; nt < 4; ++nt)
#pragma unroll
        for (int ks = 0; ks < 2; ++ks)
          o_acc[mt][nt] = MFMA(af_pH[mt][ks], bf_v[nt][ks], o_acc[mt][nt]);
  }

  // ---- final l reduction across the 16 lrow lanes ----
#pragma unroll
  for (int i = 0; i < 16; ++i) {
    float s = l_i[i];
#pragma unroll
    for (int off = 8; off >= 1; off >>= 1) s += __shfl_xor(s, off, 16);
    l_i[i] = s;
  }

  // ---- epilogue: O[b, n, h*64+dh] = o_acc / l ----
  const int b = bh / Hc, h = bh % Hc;
#pragma unroll
  for (int mt = 0; mt < 4; ++mt) {
#pragma unroll
    for (int r = 0; r < 4; ++r) {
      const float inv_l = 1.0f / l_i[mt * 4 + r];
      const int n = q0 + wave * 64 + mt * 16 + quad * 4 + r;
      const size_t base = ((size_t)b * Nc + n) * Dc + h * DHc;
#pragma unroll
      for (int nt = 0; nt < 4; ++nt)
        O[base + nt * 16 + lrow] = f2bf(o_acc[mt][nt][r] * inv_l);
    }
  }
}

// ---------------------------------------------------------------------------
extern "C" void kernel_launch(void* const* d_in, const int* in_sizes, int n_in,
                              void* d_out, int out_size, void* d_ws,
                              size_t ws_size, hipStream_t stream) {
  const float* x  = (const float*)d_in[0];
  const float* Wq = (const float*)d_in[2];
  const float* Wk = (const float*)d_in[3];
  const float* Wv = (const float*)d_in[4];
  const float* Wo = (const float*)d_in[5];

  ushortT* ws16 = (ushortT*)d_ws;
  ushortT* xb   = ws16;
  ushortT* wqb  = xb + (size_t)Mrows * Dc;
  ushortT* qkvb = wqb + 4 * (size_t)Dc * Dc;
  ushortT* qb   = qkvb;
  ushortT* kb   = qb + (size_t)Mrows * Dc;
  ushortT* vb   = kb + (size_t)Mrows * Dc;
  ushortT* aob  = vb + (size_t)Mrows * Dc;
  ushortT* wob  = wqb + 3 * (size_t)Dc * Dc;

  dim3 blk(256);
  hipLaunchKernelGGL(cvt_kernel, dim3(12288), blk, 0, stream, x, Wq, Wk, Wv, Wo,
                     ws16);

  hipLaunchKernelGGL((mfma_gemm<1>), dim3(24, Mrows / 128), blk, 0, stream, xb,
                     wqb, (void*)qkvb);

  hipLaunchKernelGGL(attn_mfma, dim3(Nc / 256, Bc * Hc), blk, 0, stream, qb,
                     kb, vb, aob);

  hipLaunchKernelGGL((mfma_gemm<0>), dim3(8, Mrows / 128), blk, 0, stream, aob,
                     wob, d_out);
}

// Round 7
// 309.770 us; speedup vs baseline: 1.6934x; 1.6105x over previous
//
#include <hip/hip_runtime.h>
#include <math.h>

// Problem constants: B=4, N=2048, D=1024, H=16, DH=64
constexpr int Bc  = 4;
constexpr int Nc  = 2048;
constexpr int Dc  = 1024;
constexpr int Hc  = 16;
constexpr int DHc = 64;
constexpr int Mrows = Bc * Nc;  // 8192

typedef unsigned short ushortT;
typedef __attribute__((ext_vector_type(8))) short bf16x8;
typedef __attribute__((ext_vector_type(4))) unsigned short u16x4;
typedef __attribute__((ext_vector_type(4))) float f32x4;

// 1/sqrt(DH) * log2(e): folded into Q so softmax is exp2(s) directly.
#define QSCALE 0.18033688011112043f

// async global->LDS, 16B per lane; LDS dest must be wave-uniform base + lane*16
#define GLD_LDS16(g, l)                                                        \
  __builtin_amdgcn_global_load_lds(                                            \
      (const __attribute__((address_space(1))) void*)(g),                      \
      (__attribute__((address_space(3))) void*)(l), 16, 0, 0)

__device__ inline ushortT f2bf(float f) {
  unsigned int u = __float_as_uint(f);
  u += 0x7fffu + ((u >> 16) & 1u);  // round-to-nearest-even
  return (ushortT)(u >> 16);
}

// fast 2^x on the transcendental pipe (v_exp_f32)
__device__ inline float fexp2(float x) { return __builtin_amdgcn_exp2f(x); }

// ---------------------------------------------------------------------------
// fp32 -> bf16 conversion of x and the 4 weight matrices (round-0 exact)
// ---------------------------------------------------------------------------
__global__ __launch_bounds__(256) void cvt_kernel(
    const float* __restrict__ x, const float* __restrict__ wq,
    const float* __restrict__ wk, const float* __restrict__ wv,
    const float* __restrict__ wo, ushortT* __restrict__ dst) {
  const int g = blockIdx.x * 256 + threadIdx.x;  // float4 index
  const float* src;
  size_t soff, doff;
  if (g < 2097152) {
    src = x;
    soff = (size_t)g * 4;
    doff = soff;
  } else {
    const int t = g - 2097152;
    const int w = t >> 18;
    const int off = t & 262143;
    src = (w == 0) ? wq : (w == 1) ? wk : (w == 2) ? wv : wo;
    soff = (size_t)off * 4;
    doff = 8388608u + (size_t)w * 1048576u + (size_t)off * 4;
  }
  float4 v = *(const float4*)(src + soff);
  ushort4 o = make_ushort4(f2bf(v.x), f2bf(v.y), f2bf(v.z), f2bf(v.w));
  *(ushort4*)(dst + doff) = o;
}

// ---------------------------------------------------------------------------
// MFMA GEMM C = A @ W^T.  BK=64 via two m97-layout 32-k panels: 32 MFMA per
// barrier pair (round-0 structure). Round-7 add: T1 XCD-aware bijective
// workgroup swizzle ONLY (nwg%8==0 for both launches: 24x64=1536, 8x64=512);
// index-only change, correctness-verified in rounds 4-6.
// QKV=1: wsel=bx>>3 selects Wq/Wk/Wv; Q output (wsel==0) pre-scaled by QSCALE.
// ---------------------------------------------------------------------------
template <int QKV>
__global__ __launch_bounds__(256) void mfma_gemm(const ushortT* __restrict__ A,
                                                 const ushortT* __restrict__ W0,
                                                 void* __restrict__ C0) {
  __shared__ ushortT As[2][128 * 32];  // [panel][row][32]
  __shared__ ushortT Bs[2][128 * 32];

  const int tid = threadIdx.x;
  const int wave = tid >> 6, lane = tid & 63;
  const int quad = lane >> 4, lrow = lane & 15;

  // T1: XCD swizzle of the flat workgroup id (bijective since nwg%8==0).
  const int gx = gridDim.x;
  const int nwg = gx * gridDim.y;
  const int orig = blockIdx.y * gx + blockIdx.x;
  const int swz = (orig & 7) * (nwg >> 3) + (orig >> 3);
  const int bx = swz % gx, by = swz / gx;

  const int wsel = QKV ? (bx >> 3) : 0;
  const int e0 = QKV ? ((bx & 7) * 128) : (bx * 128);
  const int m0 = by * 128;
  const ushortT* Wp = W0 + (size_t)wsel * (Dc * Dc);
  const float oscale = (QKV && wsel == 0) ? QSCALE : 1.0f;

  const ushortT* ag = A  + (size_t)(m0 + wave * 32 + (lane >> 2)) * Dc + (lane & 3) * 8;
  const ushortT* bg = Wp + (size_t)(e0 + wave * 32 + (lane >> 2)) * Dc + (lane & 3) * 8;
  const int lbase = wave * 1024 + lane * 8;

  f32x4 acc[4][4];
#pragma unroll
  for (int i = 0; i < 4; ++i)
#pragma unroll
    for (int j = 0; j < 4; ++j) acc[i][j] = (f32x4){0.f, 0.f, 0.f, 0.f};

  const int wm = (wave >> 1) * 64, wn = (wave & 1) * 64;

  for (int k0 = 0; k0 < Dc; k0 += 64) {
    __syncthreads();
#pragma unroll
    for (int p = 0; p < 2; ++p) {
      GLD_LDS16(ag + p * 32, &As[p][lbase]);
      GLD_LDS16(ag + p * 32 + 16 * Dc, &As[p][lbase + 512]);
      GLD_LDS16(bg + p * 32, &Bs[p][lbase]);
      GLD_LDS16(bg + p * 32 + 16 * Dc, &Bs[p][lbase + 512]);
    }
    ag += 64;
    bg += 64;
    __syncthreads();

#pragma unroll
    for (int p = 0; p < 2; ++p) {
      bf16x8 af[4], bf[4];
#pragma unroll
      for (int mt = 0; mt < 4; ++mt)
        af[mt] = *(const bf16x8*)(&As[p][(wm + mt * 16 + lrow) * 32 + quad * 8]);
#pragma unroll
      for (int nt = 0; nt < 4; ++nt)
        bf[nt] = *(const bf16x8*)(&Bs[p][(wn + nt * 16 + lrow) * 32 + quad * 8]);
#pragma unroll
      for (int mt = 0; mt < 4; ++mt)
#pragma unroll
        for (int nt = 0; nt < 4; ++nt)
          acc[mt][nt] = __builtin_amdgcn_mfma_f32_16x16x32_bf16(
              af[mt], bf[nt], acc[mt][nt], 0, 0, 0);
    }
  }

#pragma unroll
  for (int mt = 0; mt < 4; ++mt) {
#pragma unroll
    for (int nt = 0; nt < 4; ++nt) {
#pragma unroll
      for (int r = 0; r < 4; ++r) {
        const int m = m0 + wm + mt * 16 + quad * 4 + r;
        const int e = e0 + wn + nt * 16 + lrow;
        const float v = acc[mt][nt][r] * oscale;
        if (QKV) {
          const int b = m >> 11, n = m & 2047;
          const int h = e >> 6, dh = e & 63;
          ushortT* C = (ushortT*)C0 + (size_t)wsel * ((size_t)Mrows * Dc);
          C[(((size_t)(b * Hc + h)) * Nc + n) * DHc + dh] = f2bf(v);
        } else {
          ((float*)C0)[(size_t)m * Dc + e] = v;
        }
      }
    }
  }
}

// ---------------------------------------------------------------------------
// MFMA flash attention, fixed-m softmax. BQ=256, 256 threads (4 waves x 64
// Q-rows). ROUND-0 STRUCTURE EXACTLY (106 us verified: single Vt, 2 barriers
// per iter, no Ks swizzle, no setprio, Ks ping-pong distance-1, V reg
// prefetch + transposed Vt write after PV), with ONE register-neutral
// reordering:
//   softmax and PV are interleaved PER mt SUB-TILE. P is wave-local, so
//   each mt's {exp2 -> pack -> P-store -> lgkm drain -> af_p reload ->
//   8 PV MFMAs} is self-contained; PV(mt)'s MFMAs (matrix pipe) have no
//   dependence on exp2(mt+1) (VALU/trans pipe) -> cross-pipe overlap the
//   r0 all-then-all order serialized. Liveness shrinks (s_acc[mt] dies
//   after its block; af_p transient 4 regs vs 16).
// Register-wall rule (r1/r3/r5/r6): at 2 blocks/CU the unified file is
// 256/wave; o_acc+s_acc = 128 AGPR leave ~128 arch. r0 fits at 124; ANY
// added cross-iteration state spills. This change adds none.
// ---------------------------------------------------------------------------
__global__ __launch_bounds__(256, 2) void attn_mfma(const ushortT* __restrict__ Q,
                                                    const ushortT* __restrict__ K,
                                                    const ushortT* __restrict__ V,
                                                    ushortT* __restrict__ O) {
  __shared__ ushortT smemA[256 * 72];   // 36864 B (Qs staging uses first 32768)
  __shared__ ushortT Ks[2][64 * 64];    // 2 x 8192 B: [buf][c][key][32]
  __shared__ ushortT Vt[64 * 72];       // 9216 B: [dh][colp]

  const int tid = threadIdx.x;
  const int wave = tid >> 6, lane = tid & 63;
  const int quad = lane >> 4, lrow = lane & 15;
  const int bh = blockIdx.y;
  const int q0 = blockIdx.x * 256;

  const ushortT* qg = Q + (size_t)bh * Nc * DHc;
  const ushortT* kg = K + (size_t)bh * Nc * DHc;
  const ushortT* vg = V + (size_t)bh * Nc * DHc;

  // Vt staging map: thread handles keys {kq,kq+16,kq+32,kq+48} x 4 dh.
  const int kq = tid & 15;
  const int dhg = (tid >> 4) * 4;

  // ---- prologue: stage Q (256 rows), Ks[0]<-tile0, vreg<-V tile0 ----
#pragma unroll
  for (int c = 0; c < 2; ++c)
#pragma unroll
    for (int rh = 0; rh < 4; ++rh) {
      const int row = wave * 64 + rh * 16;
      GLD_LDS16(qg + (size_t)(q0 + row + (lane >> 2)) * DHc + c * 32 + (lane & 3) * 8,
                smemA + (c * 256 + row) * 32 + lane * 8);
    }
#pragma unroll
  for (int i = 0; i < 2; ++i) {
    const int cid = wave * 2 + i;
    const int c = cid & 1, kb = (cid >> 1) * 16;
    GLD_LDS16(kg + (size_t)(kb + (lane >> 2)) * DHc + c * 32 + (lane & 3) * 8,
              &Ks[0][(c * 64 + kb) * 32 + lane * 8]);
  }
  u16x4 vreg[4];
#pragma unroll
  for (int g = 0; g < 4; ++g)
    vreg[g] = *(const u16x4*)(vg + (size_t)(kq + 16 * g) * DHc + dhg);

  __syncthreads();  // Q + Ks0 staged

  // Q fragments -> registers (A-operand: m=lrow, k=quad*8+j)
  bf16x8 af_q[4][2];
#pragma unroll
  for (int mt = 0; mt < 4; ++mt)
#pragma unroll
    for (int ks = 0; ks < 2; ++ks)
      af_q[mt][ks] = *(const bf16x8*)(smemA +
          ((ks * 256 + wave * 64 + mt * 16 + lrow) * 32 + quad * 8));

  // Vt <- tile0 (transpose+permute from regs)
  {
    ushortT tmp[4][4];
#pragma unroll
    for (int g = 0; g < 4; ++g)
#pragma unroll
      for (int d = 0; d < 4; ++d) tmp[d][g] = vreg[g][d];
#pragma unroll
    for (int d = 0; d < 4; ++d)
      *(u16x4*)(Vt + (dhg + d) * 72 + kq * 4) = *(const u16x4*)tmp[d];
  }
  __syncthreads();  // af_q reads done before Ps overwrites Qs; Vt0 visible

  f32x4 o_acc[4][4];
#pragma unroll
  for (int mt = 0; mt < 4; ++mt)
#pragma unroll
    for (int nt = 0; nt < 4; ++nt) o_acc[mt][nt] = (f32x4){0.f, 0.f, 0.f, 0.f};
  float l_i[16];
#pragma unroll
  for (int i = 0; i < 16; ++i) l_i[i] = 0.f;

  for (int k0 = 0; k0 < Nc; k0 += 64) {
    const int cur = (k0 >> 6) & 1, nxt = cur ^ 1;
    const bool pref = (k0 + 64 < Nc);

    // ---- top-of-iter prefetch for tile t+1 (overlaps this whole iter) ----
    if (pref) {
#pragma unroll
      for (int i = 0; i < 2; ++i) {
        const int cid = wave * 2 + i;
        const int c = cid & 1, kb = (cid >> 1) * 16;
        GLD_LDS16(kg + (size_t)(k0 + 64 + kb + (lane >> 2)) * DHc + c * 32 + (lane & 3) * 8,
                  &Ks[nxt][(c * 64 + kb) * 32 + lane * 8]);
      }
#pragma unroll
      for (int g = 0; g < 4; ++g)
        vreg[g] = *(const u16x4*)(vg + (size_t)(k0 + 64 + kq + 16 * g) * DHc + dhg);
    }

    // ---- S = Q @ K^T (scale pre-folded into Q) ----
    bf16x8 bf_k[4][2];
#pragma unroll
    for (int nt = 0; nt < 4; ++nt)
#pragma unroll
      for (int ks = 0; ks < 2; ++ks)
        bf_k[nt][ks] = *(const bf16x8*)(&Ks[cur][(ks * 64 + nt * 16 + lrow) * 32 + quad * 8]);

    f32x4 s_acc[4][4];
#pragma unroll
    for (int mt = 0; mt < 4; ++mt)
#pragma unroll
      for (int nt = 0; nt < 4; ++nt) {
        s_acc[mt][nt] = (f32x4){0.f, 0.f, 0.f, 0.f};
#pragma unroll
        for (int ks = 0; ks < 2; ++ks)
          s_acc[mt][nt] = __builtin_amdgcn_mfma_f32_16x16x32_bf16(
              af_q[mt][ks], bf_k[nt][ks], s_acc[mt][nt], 0, 0, 0);
      }

    // ---- V fragments for this tile (B-operand), loaded up front so their
    //      latency hides under the first exp2 block ----
    bf16x8 bf_v[4][2];
#pragma unroll
    for (int nt = 0; nt < 4; ++nt)
#pragma unroll
      for (int ks = 0; ks < 2; ++ks)
        bf_v[nt][ks] = *(const bf16x8*)(Vt + (nt * 16 + lrow) * 72 + ks * 32 + quad * 8);

    // ---- interleaved softmax + PV, per mt sub-tile: exp2(mt)->P store->
    //      drain->af_p(mt) reload->8 PV MFMAs. PV(mt) overlaps exp2(mt+1)
    //      across the matrix/VALU pipes. P is wave-local: lgkm drain only,
    //      no barrier. ----
#pragma unroll
    for (int mt = 0; mt < 4; ++mt) {
#pragma unroll
      for (int r = 0; r < 4; ++r) {
        const float p0 = fexp2(s_acc[mt][0][r]);
        const float p1 = fexp2(s_acc[mt][1][r]);
        const float p2 = fexp2(s_acc[mt][2][r]);
        const float p3 = fexp2(s_acc[mt][3][r]);
        l_i[mt * 4 + r] += (p0 + p1) + (p2 + p3);
        const unsigned pk01 = __builtin_amdgcn_perm(
            __float_as_uint(p1), __float_as_uint(p0), 0x07060302u);
        const unsigned pk23 = __builtin_amdgcn_perm(
            __float_as_uint(p3), __float_as_uint(p2), 0x07060302u);
        const int row = wave * 64 + mt * 16 + quad * 4 + r;
        *(uint2*)(smemA + row * 72 + lrow * 4) = make_uint2(pk01, pk23);
      }
      asm volatile("s_waitcnt lgkmcnt(0)" ::: "memory");
      bf16x8 af_p0 = *(const bf16x8*)(smemA +
          (wave * 64 + mt * 16 + lrow) * 72 + quad * 8);
      bf16x8 af_p1 = *(const bf16x8*)(smemA +
          (wave * 64 + mt * 16 + lrow) * 72 + 32 + quad * 8);
#pragma unroll
      for (int nt = 0; nt < 4; ++nt) {
        o_acc[mt][nt] = __builtin_amdgcn_mfma_f32_16x16x32_bf16(
            af_p0, bf_v[nt][0], o_acc[mt][nt], 0, 0, 0);
        o_acc[mt][nt] = __builtin_amdgcn_mfma_f32_16x16x32_bf16(
            af_p1, bf_v[nt][1], o_acc[mt][nt], 0, 0, 0);
      }
    }

    __syncthreads();  // all waves done reading Vt (tile t)

    // ---- Vt <- tile t+1 from prefetched regs (vmcnt wait auto-inserted) ----
    if (pref) {
      ushortT tmp[4][4];
#pragma unroll
      for (int g = 0; g < 4; ++g)
#pragma unroll
        for (int d = 0; d < 4; ++d) tmp[d][g] = vreg[g][d];
#pragma unroll
      for (int d = 0; d < 4; ++d)
        *(u16x4*)(Vt + (dhg + d) * 72 + kq * 4) = *(const u16x4*)tmp[d];
    }

    // loop-boundary barrier: Vt(t+1) visible; Ks[nxt] DMA (issued a full
    // iteration ago) drained by the implicit vmcnt(0) here.
    __syncthreads();
  }

  // ---- final l reduction across the 16 lrow lanes ----
#pragma unroll
  for (int i = 0; i < 16; ++i) {
    float s = l_i[i];
#pragma unroll
    for (int off = 8; off >= 1; off >>= 1) s += __shfl_xor(s, off, 16);
    l_i[i] = s;
  }

  // ---- epilogue: O[b, n, h*64+dh] = o_acc / l ----
  const int b = bh / Hc, h = bh % Hc;
#pragma unroll
  for (int mt = 0; mt < 4; ++mt) {
#pragma unroll
    for (int r = 0; r < 4; ++r) {
      const float inv_l = 1.0f / l_i[mt * 4 + r];
      const int n = q0 + wave * 64 + mt * 16 + quad * 4 + r;
      const size_t base = ((size_t)b * Nc + n) * Dc + h * DHc;
#pragma unroll
      for (int nt = 0; nt < 4; ++nt)
        O[base + nt * 16 + lrow] = f2bf(o_acc[mt][nt][r] * inv_l);
    }
  }
}

// ---------------------------------------------------------------------------
extern "C" void kernel_launch(void* const* d_in, const int* in_sizes, int n_in,
                              void* d_out, int out_size, void* d_ws,
                              size_t ws_size, hipStream_t stream) {
  const float* x  = (const float*)d_in[0];
  const float* Wq = (const float*)d_in[2];
  const float* Wk = (const float*)d_in[3];
  const float* Wv = (const float*)d_in[4];
  const float* Wo = (const float*)d_in[5];

  ushortT* ws16 = (ushortT*)d_ws;
  ushortT* xb   = ws16;
  ushortT* wqb  = xb + (size_t)Mrows * Dc;
  ushortT* qkvb = wqb + 4 * (size_t)Dc * Dc;
  ushortT* qb   = qkvb;
  ushortT* kb   = qb + (size_t)Mrows * Dc;
  ushortT* vb   = kb + (size_t)Mrows * Dc;
  ushortT* aob  = vb + (size_t)Mrows * Dc;
  ushortT* wob  = wqb + 3 * (size_t)Dc * Dc;

  dim3 blk(256);
  hipLaunchKernelGGL(cvt_kernel, dim3(12288), blk, 0, stream, x, Wq, Wk, Wv, Wo,
                     ws16);

  hipLaunchKernelGGL((mfma_gemm<1>), dim3(24, Mrows / 128), blk, 0, stream, xb,
                     wqb, (void*)qkvb);

  hipLaunchKernelGGL(attn_mfma, dim3(Nc / 256, Bc * Hc), blk, 0, stream, qb,
                     kb, vb, aob);

  hipLaunchKernelGGL((mfma_gemm<0>), dim3(8, Mrows / 128), blk, 0, stream, aob,
                     wob, d_out);
}

// Round 8
// 301.378 us; speedup vs baseline: 1.7406x; 1.0278x over previous
//
#include <hip/hip_runtime.h>
#include <math.h>

// Problem constants: B=4, N=2048, D=1024, H=16, DH=64
constexpr int Bc  = 4;
constexpr int Nc  = 2048;
constexpr int Dc  = 1024;
constexpr int Hc  = 16;
constexpr int DHc = 64;
constexpr int Mrows = Bc * Nc;  // 8192

typedef unsigned short ushortT;
typedef __attribute__((ext_vector_type(8))) short bf16x8;
typedef __attribute__((ext_vector_type(4))) unsigned short u16x4;
typedef __attribute__((ext_vector_type(4))) float f32x4;

// 1/sqrt(DH) * log2(e): folded into Q so softmax is exp2(s) directly.
#define QSCALE 0.18033688011112043f

// async global->LDS, 16B per lane; LDS dest must be wave-uniform base + lane*16
#define GLD_LDS16(g, l)                                                        \
  __builtin_amdgcn_global_load_lds(                                            \
      (const __attribute__((address_space(1))) void*)(g),                      \
      (__attribute__((address_space(3))) void*)(l), 16, 0, 0)

__device__ inline ushortT f2bf(float f) {
  unsigned int u = __float_as_uint(f);
  u += 0x7fffu + ((u >> 16) & 1u);  // round-to-nearest-even
  return (ushortT)(u >> 16);
}

// fast 2^x on the transcendental pipe (v_exp_f32)
__device__ inline float fexp2(float x) { return __builtin_amdgcn_exp2f(x); }

// ---------------------------------------------------------------------------
// fp32 -> bf16 conversion of x and the 4 weight matrices (round-0 exact)
// ---------------------------------------------------------------------------
__global__ __launch_bounds__(256) void cvt_kernel(
    const float* __restrict__ x, const float* __restrict__ wq,
    const float* __restrict__ wk, const float* __restrict__ wv,
    const float* __restrict__ wo, ushortT* __restrict__ dst) {
  const int g = blockIdx.x * 256 + threadIdx.x;  // float4 index
  const float* src;
  size_t soff, doff;
  if (g < 2097152) {
    src = x;
    soff = (size_t)g * 4;
    doff = soff;
  } else {
    const int t = g - 2097152;
    const int w = t >> 18;
    const int off = t & 262143;
    src = (w == 0) ? wq : (w == 1) ? wk : (w == 2) ? wv : wo;
    soff = (size_t)off * 4;
    doff = 8388608u + (size_t)w * 1048576u + (size_t)off * 4;
  }
  float4 v = *(const float4*)(src + soff);
  ushort4 o = make_ushort4(f2bf(v.x), f2bf(v.y), f2bf(v.z), f2bf(v.w));
  *(ushort4*)(dst + doff) = o;
}

// ---------------------------------------------------------------------------
// MFMA GEMM C = A @ W^T.  BK=64 via two m97-layout 32-k panels: 32 MFMA per
// barrier pair (round-0 structure) + T1 XCD-aware bijective swizzle
// (measured ~neutral-to-positive vs r0: r7 GEMM-side delta -0.9 us; kept).
// QKV=1: wsel=bx>>3 selects Wq/Wk/Wv; Q output (wsel==0) pre-scaled by QSCALE.
// ---------------------------------------------------------------------------
template <int QKV>
__global__ __launch_bounds__(256) void mfma_gemm(const ushortT* __restrict__ A,
                                                 const ushortT* __restrict__ W0,
                                                 void* __restrict__ C0) {
  __shared__ ushortT As[2][128 * 32];  // [panel][row][32]
  __shared__ ushortT Bs[2][128 * 32];

  const int tid = threadIdx.x;
  const int wave = tid >> 6, lane = tid & 63;
  const int quad = lane >> 4, lrow = lane & 15;

  // T1: XCD swizzle of the flat workgroup id (bijective since nwg%8==0).
  const int gx = gridDim.x;
  const int nwg = gx * gridDim.y;
  const int orig = blockIdx.y * gx + blockIdx.x;
  const int swz = (orig & 7) * (nwg >> 3) + (orig >> 3);
  const int bx = swz % gx, by = swz / gx;

  const int wsel = QKV ? (bx >> 3) : 0;
  const int e0 = QKV ? ((bx & 7) * 128) : (bx * 128);
  const int m0 = by * 128;
  const ushortT* Wp = W0 + (size_t)wsel * (Dc * Dc);
  const float oscale = (QKV && wsel == 0) ? QSCALE : 1.0f;

  const ushortT* ag = A  + (size_t)(m0 + wave * 32 + (lane >> 2)) * Dc + (lane & 3) * 8;
  const ushortT* bg = Wp + (size_t)(e0 + wave * 32 + (lane >> 2)) * Dc + (lane & 3) * 8;
  const int lbase = wave * 1024 + lane * 8;

  f32x4 acc[4][4];
#pragma unroll
  for (int i = 0; i < 4; ++i)
#pragma unroll
    for (int j = 0; j < 4; ++j) acc[i][j] = (f32x4){0.f, 0.f, 0.f, 0.f};

  const int wm = (wave >> 1) * 64, wn = (wave & 1) * 64;

  for (int k0 = 0; k0 < Dc; k0 += 64) {
    __syncthreads();
#pragma unroll
    for (int p = 0; p < 2; ++p) {
      GLD_LDS16(ag + p * 32, &As[p][lbase]);
      GLD_LDS16(ag + p * 32 + 16 * Dc, &As[p][lbase + 512]);
      GLD_LDS16(bg + p * 32, &Bs[p][lbase]);
      GLD_LDS16(bg + p * 32 + 16 * Dc, &Bs[p][lbase + 512]);
    }
    ag += 64;
    bg += 64;
    __syncthreads();

#pragma unroll
    for (int p = 0; p < 2; ++p) {
      bf16x8 af[4], bf[4];
#pragma unroll
      for (int mt = 0; mt < 4; ++mt)
        af[mt] = *(const bf16x8*)(&As[p][(wm + mt * 16 + lrow) * 32 + quad * 8]);
#pragma unroll
      for (int nt = 0; nt < 4; ++nt)
        bf[nt] = *(const bf16x8*)(&Bs[p][(wn + nt * 16 + lrow) * 32 + quad * 8]);
#pragma unroll
      for (int mt = 0; mt < 4; ++mt)
#pragma unroll
        for (int nt = 0; nt < 4; ++nt)
          acc[mt][nt] = __builtin_amdgcn_mfma_f32_16x16x32_bf16(
              af[mt], bf[nt], acc[mt][nt], 0, 0, 0);
    }
  }

#pragma unroll
  for (int mt = 0; mt < 4; ++mt) {
#pragma unroll
    for (int nt = 0; nt < 4; ++nt) {
#pragma unroll
      for (int r = 0; r < 4; ++r) {
        const int m = m0 + wm + mt * 16 + quad * 4 + r;
        const int e = e0 + wn + nt * 16 + lrow;
        const float v = acc[mt][nt][r] * oscale;
        if (QKV) {
          const int b = m >> 11, n = m & 2047;
          const int h = e >> 6, dh = e & 63;
          ushortT* C = (ushortT*)C0 + (size_t)wsel * ((size_t)Mrows * Dc);
          C[(((size_t)(b * Hc + h)) * Nc + n) * DHc + dh] = f2bf(v);
        } else {
          ((float*)C0)[(size_t)m * Dc + e] = v;
        }
      }
    }
  }
}

// ---------------------------------------------------------------------------
// MFMA flash attention, fixed-m softmax. Round-8: BQ=128 (4 waves x 32
// Q-rows). Structure is r0 EXACT (single Vt, 2 barriers/iter, Ks ping-pong
// distance-1, V reg prefetch + post-PV Vt write, softmax-then-PV order, no
// swizzle, no setprio) -- only the tile is halved.
// Rationale (7-round register-wall law): the BQ=256 tile's o_acc+s_acc =
// 128 AGPR + ~124 arch VGPR fills the wave's unified budget at 2 waves/SIMD;
// no pipelining fits. Halving the tile: acc = 64 AGPR, arch ~100-110 ->
// unified ~170 -> (64-reg granule) 192 -> 3 waves/SIMD; LDS 44032 B -> 3
// blocks/CU. 8 -> 12 waves/CU from 3 independent blocks at different phases
// = the latency hiding this issue-bound kernel lacks (HBM 16%, conflicts
// and traffic proven non-levers in r3/r4). Cost: 2x K/V staging per Q-row
// (LDS/HBM headroom is huge). Downside bounded: if regs land >192 unified,
// residency stays 2/SIMD and perf ~= r0 -- no new live state exists.
// ---------------------------------------------------------------------------
__global__ __launch_bounds__(256, 2) void attn_mfma(const ushortT* __restrict__ Q,
                                                    const ushortT* __restrict__ K,
                                                    const ushortT* __restrict__ V,
                                                    ushortT* __restrict__ O) {
  __shared__ ushortT smemA[128 * 72];   // 18432 B (Qs staging uses first 16384)
  __shared__ ushortT Ks[2][64 * 64];    // 2 x 8192 B: [buf][c][key][32]
  __shared__ ushortT Vt[64 * 72];       // 9216 B: [dh][colp]

  const int tid = threadIdx.x;
  const int wave = tid >> 6, lane = tid & 63;
  const int quad = lane >> 4, lrow = lane & 15;
  const int bh = blockIdx.y;
  const int q0 = blockIdx.x * 128;

  const ushortT* qg = Q + (size_t)bh * Nc * DHc;
  const ushortT* kg = K + (size_t)bh * Nc * DHc;
  const ushortT* vg = V + (size_t)bh * Nc * DHc;

  // Vt staging map: thread handles keys {kq,kq+16,kq+32,kq+48} x 4 dh.
  const int kq = tid & 15;
  const int dhg = (tid >> 4) * 4;

  // ---- prologue: stage Q (128 rows), Ks[0]<-tile0, vreg<-V tile0 ----
#pragma unroll
  for (int c = 0; c < 2; ++c)
#pragma unroll
    for (int rh = 0; rh < 2; ++rh) {
      const int row = wave * 32 + rh * 16;
      GLD_LDS16(qg + (size_t)(q0 + row + (lane >> 2)) * DHc + c * 32 + (lane & 3) * 8,
                smemA + (c * 128 + row) * 32 + lane * 8);
    }
#pragma unroll
  for (int i = 0; i < 2; ++i) {
    const int cid = wave * 2 + i;
    const int c = cid & 1, kb = (cid >> 1) * 16;
    GLD_LDS16(kg + (size_t)(kb + (lane >> 2)) * DHc + c * 32 + (lane & 3) * 8,
              &Ks[0][(c * 64 + kb) * 32 + lane * 8]);
  }
  u16x4 vreg[4];
#pragma unroll
  for (int g = 0; g < 4; ++g)
    vreg[g] = *(const u16x4*)(vg + (size_t)(kq + 16 * g) * DHc + dhg);

  __syncthreads();  // Q + Ks0 staged

  // Q fragments -> registers (A-operand: m=lrow, k=quad*8+j)
  bf16x8 af_q[2][2];
#pragma unroll
  for (int mt = 0; mt < 2; ++mt)
#pragma unroll
    for (int ks = 0; ks < 2; ++ks)
      af_q[mt][ks] = *(const bf16x8*)(smemA +
          ((ks * 128 + wave * 32 + mt * 16 + lrow) * 32 + quad * 8));

  // Vt <- tile0 (transpose+permute from regs)
  {
    ushortT tmp[4][4];
#pragma unroll
    for (int g = 0; g < 4; ++g)
#pragma unroll
      for (int d = 0; d < 4; ++d) tmp[d][g] = vreg[g][d];
#pragma unroll
    for (int d = 0; d < 4; ++d)
      *(u16x4*)(Vt + (dhg + d) * 72 + kq * 4) = *(const u16x4*)tmp[d];
  }
  __syncthreads();  // af_q reads done before Ps overwrites Qs; Vt0 visible

  f32x4 o_acc[2][4];
#pragma unroll
  for (int mt = 0; mt < 2; ++mt)
#pragma unroll
    for (int nt = 0; nt < 4; ++nt) o_acc[mt][nt] = (f32x4){0.f, 0.f, 0.f, 0.f};
  float l_i[8];
#pragma unroll
  for (int i = 0; i < 8; ++i) l_i[i] = 0.f;

  for (int k0 = 0; k0 < Nc; k0 += 64) {
    const int cur = (k0 >> 6) & 1, nxt = cur ^ 1;
    const bool pref = (k0 + 64 < Nc);

    // ---- top-of-iter prefetch for tile t+1 (overlaps this whole iter) ----
    if (pref) {
#pragma unroll
      for (int i = 0; i < 2; ++i) {
        const int cid = wave * 2 + i;
        const int c = cid & 1, kb = (cid >> 1) * 16;
        GLD_LDS16(kg + (size_t)(k0 + 64 + kb + (lane >> 2)) * DHc + c * 32 + (lane & 3) * 8,
                  &Ks[nxt][(c * 64 + kb) * 32 + lane * 8]);
      }
#pragma unroll
      for (int g = 0; g < 4; ++g)
        vreg[g] = *(const u16x4*)(vg + (size_t)(k0 + 64 + kq + 16 * g) * DHc + dhg);
    }

    // ---- S = Q @ K^T (scale pre-folded into Q) ----
    bf16x8 bf_k[4][2];
#pragma unroll
    for (int nt = 0; nt < 4; ++nt)
#pragma unroll
      for (int ks = 0; ks < 2; ++ks)
        bf_k[nt][ks] = *(const bf16x8*)(&Ks[cur][(ks * 64 + nt * 16 + lrow) * 32 + quad * 8]);

    f32x4 s_acc[2][4];
#pragma unroll
    for (int mt = 0; mt < 2; ++mt)
#pragma unroll
      for (int nt = 0; nt < 4; ++nt) {
        s_acc[mt][nt] = (f32x4){0.f, 0.f, 0.f, 0.f};
#pragma unroll
        for (int ks = 0; ks < 2; ++ks)
          s_acc[mt][nt] = __builtin_amdgcn_mfma_f32_16x16x32_bf16(
              af_q[mt][ks], bf_k[nt][ks], s_acc[mt][nt], 0, 0, 0);
      }

    // ---- P = exp2(S); partial row-sums; P -> LDS (bf16, colp layout) ----
#pragma unroll
    for (int mt = 0; mt < 2; ++mt) {
#pragma unroll
      for (int r = 0; r < 4; ++r) {
        const float p0 = fexp2(s_acc[mt][0][r]);
        const float p1 = fexp2(s_acc[mt][1][r]);
        const float p2 = fexp2(s_acc[mt][2][r]);
        const float p3 = fexp2(s_acc[mt][3][r]);
        l_i[mt * 4 + r] += (p0 + p1) + (p2 + p3);
        const unsigned pk01 = __builtin_amdgcn_perm(
            __float_as_uint(p1), __float_as_uint(p0), 0x07060302u);
        const unsigned pk23 = __builtin_amdgcn_perm(
            __float_as_uint(p3), __float_as_uint(p2), 0x07060302u);
        const int row = wave * 32 + mt * 16 + quad * 4 + r;
        *(uint2*)(smemA + row * 72 + lrow * 4) = make_uint2(pk01, pk23);
      }
    }
    // P is wave-local: drain LDS writes, no barrier.
    asm volatile("s_waitcnt lgkmcnt(0)" ::: "memory");

    // ---- O += P @ V  (reads the whole Vt) ----
    bf16x8 af_p[2][2], bf_v[4][2];
#pragma unroll
    for (int mt = 0; mt < 2; ++mt)
#pragma unroll
      for (int ks = 0; ks < 2; ++ks)
        af_p[mt][ks] = *(const bf16x8*)(smemA +
            (wave * 32 + mt * 16 + lrow) * 72 + ks * 32 + quad * 8);
#pragma unroll
    for (int nt = 0; nt < 4; ++nt)
#pragma unroll
      for (int ks = 0; ks < 2; ++ks)
        bf_v[nt][ks] = *(const bf16x8*)(Vt + (nt * 16 + lrow) * 72 + ks * 32 + quad * 8);
#pragma unroll
    for (int mt = 0; mt < 2; ++mt)
#pragma unroll
      for (int nt = 0; nt < 4; ++nt)
#pragma unroll
        for (int ks = 0; ks < 2; ++ks)
          o_acc[mt][nt] = __builtin_amdgcn_mfma_f32_16x16x32_bf16(
              af_p[mt][ks], bf_v[nt][ks], o_acc[mt][nt], 0, 0, 0);

    __syncthreads();  // all waves done reading Vt (tile t)

    // ---- Vt <- tile t+1 from prefetched regs (vmcnt wait auto-inserted) ----
    if (pref) {
      ushortT tmp[4][4];
#pragma unroll
      for (int g = 0; g < 4; ++g)
#pragma unroll
        for (int d = 0; d < 4; ++d) tmp[d][g] = vreg[g][d];
#pragma unroll
      for (int d = 0; d < 4; ++d)
        *(u16x4*)(Vt + (dhg + d) * 72 + kq * 4) = *(const u16x4*)tmp[d];
    }

    // loop-boundary barrier: Vt(t+1) visible; Ks[nxt] DMA (issued a full
    // iteration ago) drained by the implicit vmcnt(0) here.
    __syncthreads();
  }

  // ---- final l reduction across the 16 lrow lanes ----
#pragma unroll
  for (int i = 0; i < 8; ++i) {
    float s = l_i[i];
#pragma unroll
    for (int off = 8; off >= 1; off >>= 1) s += __shfl_xor(s, off, 16);
    l_i[i] = s;
  }

  // ---- epilogue: O[b, n, h*64+dh] = o_acc / l ----
  const int b = bh / Hc, h = bh % Hc;
#pragma unroll
  for (int mt = 0; mt < 2; ++mt) {
#pragma unroll
    for (int r = 0; r < 4; ++r) {
      const float inv_l = 1.0f / l_i[mt * 4 + r];
      const int n = q0 + wave * 32 + mt * 16 + quad * 4 + r;
      const size_t base = ((size_t)b * Nc + n) * Dc + h * DHc;
#pragma unroll
      for (int nt = 0; nt < 4; ++nt)
        O[base + nt * 16 + lrow] = f2bf(o_acc[mt][nt][r] * inv_l);
    }
  }
}

// ---------------------------------------------------------------------------
extern "C" void kernel_launch(void* const* d_in, const int* in_sizes, int n_in,
                              void* d_out, int out_size, void* d_ws,
                              size_t ws_size, hipStream_t stream) {
  const float* x  = (const float*)d_in[0];
  const float* Wq = (const float*)d_in[2];
  const float* Wk = (const float*)d_in[3];
  const float* Wv = (const float*)d_in[4];
  const float* Wo = (const float*)d_in[5];

  ushortT* ws16 = (ushortT*)d_ws;
  ushortT* xb   = ws16;
  ushortT* wqb  = xb + (size_t)Mrows * Dc;
  ushortT* qkvb = wqb + 4 * (size_t)Dc * Dc;
  ushortT* qb   = qkvb;
  ushortT* kb   = qb + (size_t)Mrows * Dc;
  ushortT* vb   = kb + (size_t)Mrows * Dc;
  ushortT* aob  = vb + (size_t)Mrows * Dc;
  ushortT* wob  = wqb + 3 * (size_t)Dc * Dc;

  dim3 blk(256);
  hipLaunchKernelGGL(cvt_kernel, dim3(12288), blk, 0, stream, x, Wq, Wk, Wv, Wo,
                     ws16);

  hipLaunchKernelGGL((mfma_gemm<1>), dim3(24, Mrows / 128), blk, 0, stream, xb,
                     wqb, (void*)qkvb);

  hipLaunchKernelGGL(attn_mfma, dim3(Nc / 128, Bc * Hc), blk, 0, stream, qb,
                     kb, vb, aob);

  hipLaunchKernelGGL((mfma_gemm<0>), dim3(8, Mrows / 128), blk, 0, stream, aob,
                     wob, d_out);
}